// Round 7
// baseline (302.476 us; speedup 1.0000x reference)
//
#include <hip/hip_runtime.h>

#define NN 4096
#define CC 32
#define TT 12
#define BB 4
#define BT 48          // BB*TT
#define NC 1536        // BT*CC
#define MAXD 192       // mean degree ~82; P(deg>192) astronomically small
#define FW 512         // features per chunk (8/lane, 16B); chunk slice = 4096*1KB = 4MB
#define NCH 3          // NC / FW
#define STP 36         // k_trans LDS row stride (ushorts)

typedef float f32x4 __attribute__((ext_vector_type(4)));
typedef short short8 __attribute__((ext_vector_type(8)));
typedef unsigned short ushort8 __attribute__((ext_vector_type(8)));

__device__ __forceinline__ float bf2f(unsigned short h) {
  return __uint_as_float(((unsigned int)h) << 16);
}
__device__ __forceinline__ unsigned short f2bf(float f) {
  unsigned int u = __float_as_uint(f);
  return (unsigned short)((u + 0x7FFFu + ((u >> 16) & 1u)) >> 16);  // RNE
}
__device__ __forceinline__ float blo(unsigned int w) { return __uint_as_float(w << 16); }
__device__ __forceinline__ float bhi(unsigned int w) { return __uint_as_float(w & 0xFFFF0000u); }

// ---- fused: atomic adjacency compaction (blocks [0,NN)) + x transpose
// (blocks [NN, NN+1024)). Both halves individually proven (round-0..3 code);
// fusion = disjoint grid ranges, saves one launch gap and overlaps the two
// streaming passes. (Round-6 ballot build REGRESSED -- serialized ballot
// chain; reverted to the atomic version.)
__global__ __launch_bounds__(256) void k_build_trans(const float* __restrict__ adj,
                                                     const float* __restrict__ x,
                                                     uint2* __restrict__ edges,
                                                     int* __restrict__ deg,
                                                     float* __restrict__ dis,
                                                     unsigned short* __restrict__ H) {
  __shared__ unsigned short sT[192 * STP];
  __shared__ int cnt;
  if (blockIdx.x < NN) {
    int m = blockIdx.x;
    if (threadIdx.x == 0) cnt = 0;
    __syncthreads();
    unsigned int* ecol = (unsigned int*)(edges + m * MAXD);
    const uint4* row = (const uint4*)(adj + (size_t)m * NN);
    for (int i = threadIdx.x; i < NN / 4; i += 256) {
      uint4 v = row[i];
      unsigned int ws[4] = {v.x, v.y, v.z, v.w};
      #pragma unroll
      for (int k = 0; k < 4; ++k) {
        if (ws[k] != 0) {
          int p = atomicAdd(&cnt, 1);
          if (p < MAXD) ecol[p * 2] = (unsigned int)(i * 4 + k);
        }
      }
    }
    __syncthreads();
    if (threadIdx.x == 0) {
      int d = cnt < MAXD ? cnt : MAXD;
      deg[m] = d;
      dis[m] = d > 0 ? (float)(1.0 / sqrt((double)d)) : 0.0f;
    }
  } else {
    int bx = blockIdx.x - NN;
    int b = bx >> 8;
    int n0 = (bx & 255) * 16;
    int c = threadIdx.x >> 3;        // 32 c-groups
    int l8 = threadIdx.x & 7;
    size_t base = ((size_t)(b * CC + c) * NN + n0) * TT;  // 192 contiguous floats
    #pragma unroll
    for (int it = 0; it < 6; ++it) {
      int j0 = it * 32 + l8 * 4;                 // j = nl*12 + t
      float4 f = *(const float4*)(x + base + j0);
      sT[(j0 + 0) * STP + c] = f2bf(f.x);
      sT[(j0 + 1) * STP + c] = f2bf(f.y);
      sT[(j0 + 2) * STP + c] = f2bf(f.z);
      sT[(j0 + 3) * STP + c] = f2bf(f.w);
    }
    __syncthreads();
    #pragma unroll
    for (int k = 0; k < 6; ++k) {
      int p = (threadIdx.x >> 3) + 32 * k;       // 192 (nl,t) runs
      int nl = p / TT, t = p - nl * TT;
      ushort4 v = *(const ushort4*)&sT[p * STP + l8 * 4];
      size_t off = ((size_t)(n0 + nl) * BT + b * TT + t) * CC + l8 * 4;
      *(ushort4*)(H + off) = v;
    }
  }
}

// ---- edges[].y = dis[col]; pad edge list to multiple of 16 with {m, 0} dummies.
__global__ __launch_bounds__(192) void k_wt(uint2* __restrict__ edges,
                                            const int* __restrict__ deg,
                                            int* __restrict__ degp,
                                            const float* __restrict__ dis) {
  int m = blockIdx.x;
  int j = threadIdx.x;
  int d = deg[m];
  int dp = (d + 15) & ~15;
  if (j < d) {
    unsigned int* e = (unsigned int*)(edges + m * MAXD + j);
    e[1] = __float_as_uint(dis[e[0]]);
  } else if (j < dp) {
    edges[m * MAXD + j] = make_uint2((unsigned int)m, 0u);  // weight 0.0f
  }
  if (j == 0) degp[m] = dp;
}

// ---- pure gather (v3, proven 52 us): D[m,q] = dis[m]*sum_e dis[col]*S[col,q]
__global__ __launch_bounds__(1024) void k_gather(const unsigned short* __restrict__ S,
                                                 const uint2* __restrict__ edges,
                                                 const int* __restrict__ degp,
                                                 const float* __restrict__ dis,
                                                 unsigned short* __restrict__ D) {
  int tid = threadIdx.x;
  int wid = __builtin_amdgcn_readfirstlane(tid >> 6);
  int lane = tid & 63;
  int m = blockIdx.x * 16 + wid;
  int d = degp[m];                      // padded to x16
  float dm = dis[m];
  const uint2* ep = edges + (size_t)m * MAXD;      // wave-uniform stream
  const unsigned short* Sy = S + blockIdx.y * FW;  // uniform base
  int lo2 = lane * 8;                              // per-lane ushort offset (16B)
  float a0 = 0.f, a1 = 0.f, a2 = 0.f, a3 = 0.f;
  float a4 = 0.f, a5 = 0.f, a6 = 0.f, a7 = 0.f;
  for (int e = 0; e < d; e += 8) {
    uint4 hv[8];
    float w[8];
    #pragma unroll
    for (int k = 0; k < 8; ++k) {
      uint2 ew = ep[e + k];             // scalar (batched s_load)
      w[k] = __uint_as_float(ew.y);
      hv[k] = *(const uint4*)(Sy + (int)ew.x * NC + lo2);
    }
    #pragma unroll
    for (int k = 0; k < 8; ++k) {
      float wk = w[k];
      a0 = fmaf(wk, blo(hv[k].x), a0); a1 = fmaf(wk, bhi(hv[k].x), a1);
      a2 = fmaf(wk, blo(hv[k].y), a2); a3 = fmaf(wk, bhi(hv[k].y), a3);
      a4 = fmaf(wk, blo(hv[k].z), a4); a5 = fmaf(wk, bhi(hv[k].z), a5);
      a6 = fmaf(wk, blo(hv[k].w), a6); a7 = fmaf(wk, bhi(hv[k].w), a7);
    }
  }
  int fo = blockIdx.y * FW + lo2;
  ushort8 o;
  o[0] = f2bf(dm * a0); o[1] = f2bf(dm * a1);
  o[2] = f2bf(dm * a2); o[3] = f2bf(dm * a3);
  o[4] = f2bf(dm * a4); o[5] = f2bf(dm * a5);
  o[6] = f2bf(dm * a6); o[7] = f2bf(dm * a7);
  *(ushort8*)(D + (size_t)m * NC + fo) = o;
}

// ---- gather2 + channel mix, fused. Wave-task = (node m, chunk y) holds the
// full 16 bt-rows x 32 c tile of G2 in accumulators -- exactly one MFMA
// A-fragment tile. Epilogue: round accs to bf16 (bit-identical to the old
// global G2), bounce via 1KB wave-private LDS into MFMA lane layout, load
// matching H/G1 fragments from global, rebuild W fragments (same ops/order
// as old k_mix), identical 6-MFMA chain, per-quad float4 stores (4-aligned
// t-pieces never cross a b boundary since 12 % 4 == 0). Output values are
// bit-identical to the old k_mix. Kills k_mix's 62 MB pass, the G2
// write+read round-trip, and 2 launch gaps.
__global__ __launch_bounds__(1024, 8) void k_gather_mix(
    const unsigned short* __restrict__ G1,   // gathered source
    const unsigned short* __restrict__ H,
    const uint2* __restrict__ edges,
    const int* __restrict__ degp,
    const float* __restrict__ dis,
    const float* __restrict__ W,
    const float* __restrict__ bias,
    float* __restrict__ out) {
  __shared__ __align__(16) unsigned short sG2[16][16 * CC];   // 16 KB, wave-private tiles
  int tid = threadIdx.x;
  int wid = __builtin_amdgcn_readfirstlane(tid >> 6);
  int lane = tid & 63;
  int m = blockIdx.x * 16 + wid;
  int y = blockIdx.y;
  int d = degp[m];                      // padded to x16
  float dm = dis[m];
  const uint2* ep = edges + (size_t)m * MAXD;
  const unsigned short* Sy = G1 + y * FW;
  int lo2 = lane * 8;
  float a0 = 0.f, a1 = 0.f, a2 = 0.f, a3 = 0.f;
  float a4 = 0.f, a5 = 0.f, a6 = 0.f, a7 = 0.f;
  for (int e = 0; e < d; e += 8) {
    uint4 hv[8];
    float w[8];
    #pragma unroll
    for (int k = 0; k < 8; ++k) {
      uint2 ew = ep[e + k];
      w[k] = __uint_as_float(ew.y);
      hv[k] = *(const uint4*)(Sy + (int)ew.x * NC + lo2);
    }
    #pragma unroll
    for (int k = 0; k < 8; ++k) {
      float wk = w[k];
      a0 = fmaf(wk, blo(hv[k].x), a0); a1 = fmaf(wk, bhi(hv[k].x), a1);
      a2 = fmaf(wk, blo(hv[k].y), a2); a3 = fmaf(wk, bhi(hv[k].y), a3);
      a4 = fmaf(wk, blo(hv[k].z), a4); a5 = fmaf(wk, bhi(hv[k].z), a5);
      a6 = fmaf(wk, blo(hv[k].w), a6); a7 = fmaf(wk, bhi(hv[k].w), a7);
    }
  }
  __builtin_amdgcn_sched_barrier(0);
  // G2 tile, bf16 (bit-identical to old global G2 values)
  ushort8 go;
  go[0] = f2bf(dm * a0); go[1] = f2bf(dm * a1);
  go[2] = f2bf(dm * a2); go[3] = f2bf(dm * a3);
  go[4] = f2bf(dm * a4); go[5] = f2bf(dm * a5);
  go[6] = f2bf(dm * a6); go[7] = f2bf(dm * a7);
  // stash to wave-private LDS tile: lane holds row lane>>2, c-chunk (lane&3)*8
  *(ushort8*)&sG2[wid][(lane >> 2) * CC + (lane & 3) * 8] = go;
  // MFMA fragments (A-frag lane layout: row = lane&15, k-chunk = (lane>>4)*8)
  int lm = lane & 15, quad = lane >> 4;
  size_t abase = ((size_t)m * BT + y * 16 + lm) * CC + quad * 8;
  short8 af0 = *(const short8*)(H + abase);
  short8 af1 = *(const short8*)(G1 + abase);
  short8 af2 = *(const short8*)&sG2[wid][lm * CC + quad * 8];
  // per-quad store geometry: bt piece start (4-aligned, never crosses b)
  int bt0 = y * 16 + quad * 4;
  int b = bt0 / TT, t0 = bt0 - b * TT;
  #pragma unroll
  for (int h = 0; h < 2; ++h) {
    float bs = bias[h * 16 + lm];
    f32x4 acc = {bs, bs, bs, bs};
    #pragma unroll
    for (int g = 0; g < 3; ++g) {
      short8 vh, vl;
      #pragma unroll
      for (int j = 0; j < 8; ++j) {
        int r = quad * 8 + j, c = h * 16 + lm;
        float w0 = W[(0 * CC + r) * CC + c];
        float w1 = W[(1 * CC + r) * CC + c];
        float w2 = W[(2 * CC + r) * CC + c];
        float w = (g == 0) ? (w0 + w1 + w2)
                 : (g == 1) ? (-w1 - 4.f * w2)
                            : (2.f * w2);
        unsigned short hi = f2bf(w);
        vh[j] = (short)hi;
        vl[j] = (short)f2bf(w - bf2f(hi));
      }
      short8 af = (g == 0) ? af0 : (g == 1) ? af1 : af2;
      acc = __builtin_amdgcn_mfma_f32_16x16x32_bf16(af, vh, acc, 0, 0, 0);
      acc = __builtin_amdgcn_mfma_f32_16x16x32_bf16(af, vl, acc, 0, 0, 0);
    }
    int o = h * 16 + lm;
    *(f32x4*)(out + ((size_t)(b * CC + o) * NN + m) * TT + t0) = acc;
  }
}

extern "C" void kernel_launch(void* const* d_in, const int* in_sizes, int n_in,
                              void* d_out, int out_size, void* d_ws, size_t ws_size,
                              hipStream_t stream) {
  const float* x    = (const float*)d_in[0];
  const float* adj  = (const float*)d_in[1];
  const float* wgt  = (const float*)d_in[2];
  const float* bias = (const float*)d_in[3];
  char* ws = (char*)d_ws;
  float* dis  = (float*)ws;                                 // 16 KB
  int*   deg  = (int*)(ws + 16384);                         // 16 KB
  int*   degp = (int*)(ws + 32768);                         // 16 KB
  uint2* edges = (uint2*)(ws + 49152);                      // 6.29 MB
  char* p = ws + 49152 + (size_t)NN * MAXD * 8;
  unsigned short* H  = (unsigned short*)p;                  // 12.58 MB
  unsigned short* G1 = (unsigned short*)(p + (size_t)NN * NC * 2);

  k_build_trans<<<NN + 1024, 256, 0, stream>>>(adj, x, edges, deg, dis, H);
  k_wt<<<NN, 192, 0, stream>>>(edges, deg, degp, dis);
  k_gather<<<dim3(NN / 16, NCH), 1024, 0, stream>>>(H, edges, degp, dis, G1);
  k_gather_mix<<<dim3(NN / 16, NCH), 1024, 0, stream>>>(G1, H, edges, degp, dis,
                                                        wgt, bias, (float*)d_out);
}

// Round 8
// 254.613 us; speedup vs baseline: 1.1880x; 1.1880x over previous
//
#include <hip/hip_runtime.h>

#define NN 4096
#define CC 32
#define TT 12
#define BB 4
#define BT 48          // BB*TT
#define NC 1536        // BT*CC
#define MAXD 192       // mean degree ~82; P(deg>192) astronomically small
#define FW 512         // features per chunk (8/lane, 16B); chunk slice = 4096*1KB = 4MB
#define NCH 3          // NC / FW
#define STP 36         // k_trans LDS row stride (ushorts)
#define SOP 33         // k_mix LDS row stride (floats)

typedef float f32x4 __attribute__((ext_vector_type(4)));
typedef short short8 __attribute__((ext_vector_type(8)));
typedef unsigned short ushort8 __attribute__((ext_vector_type(8)));

__device__ __forceinline__ float bf2f(unsigned short h) {
  return __uint_as_float(((unsigned int)h) << 16);
}
__device__ __forceinline__ unsigned short f2bf(float f) {
  unsigned int u = __float_as_uint(f);
  return (unsigned short)((u + 0x7FFFu + ((u >> 16) & 1u)) >> 16);  // RNE
}
__device__ __forceinline__ float blo(unsigned int w) { return __uint_as_float(w << 16); }
__device__ __forceinline__ float bhi(unsigned int w) { return __uint_as_float(w & 0xFFFF0000u); }

// ---- fused: atomic adjacency compaction (blocks [0,NN)) + x transpose
// (blocks [NN, NN+1024)). Disjoint grid ranges; overlapped streaming passes.
__global__ __launch_bounds__(256) void k_build_trans(const float* __restrict__ adj,
                                                     const float* __restrict__ x,
                                                     uint2* __restrict__ edges,
                                                     int* __restrict__ deg,
                                                     float* __restrict__ dis,
                                                     unsigned short* __restrict__ H) {
  __shared__ unsigned short sT[192 * STP];
  __shared__ int cnt;
  if (blockIdx.x < NN) {
    int m = blockIdx.x;
    if (threadIdx.x == 0) cnt = 0;
    __syncthreads();
    unsigned int* ecol = (unsigned int*)(edges + m * MAXD);
    const uint4* row = (const uint4*)(adj + (size_t)m * NN);
    for (int i = threadIdx.x; i < NN / 4; i += 256) {
      uint4 v = row[i];
      unsigned int ws[4] = {v.x, v.y, v.z, v.w};
      #pragma unroll
      for (int k = 0; k < 4; ++k) {
        if (ws[k] != 0) {
          int p = atomicAdd(&cnt, 1);
          if (p < MAXD) ecol[p * 2] = (unsigned int)(i * 4 + k);
        }
      }
    }
    __syncthreads();
    if (threadIdx.x == 0) {
      int d = cnt < MAXD ? cnt : MAXD;
      deg[m] = d;
      dis[m] = d > 0 ? (float)(1.0 / sqrt((double)d)) : 0.0f;
    }
  } else {
    int bx = blockIdx.x - NN;
    int b = bx >> 8;
    int n0 = (bx & 255) * 16;
    int c = threadIdx.x >> 3;        // 32 c-groups
    int l8 = threadIdx.x & 7;
    size_t base = ((size_t)(b * CC + c) * NN + n0) * TT;  // 192 contiguous floats
    #pragma unroll
    for (int it = 0; it < 6; ++it) {
      int j0 = it * 32 + l8 * 4;                 // j = nl*12 + t
      float4 f = *(const float4*)(x + base + j0);
      sT[(j0 + 0) * STP + c] = f2bf(f.x);
      sT[(j0 + 1) * STP + c] = f2bf(f.y);
      sT[(j0 + 2) * STP + c] = f2bf(f.z);
      sT[(j0 + 3) * STP + c] = f2bf(f.w);
    }
    __syncthreads();
    #pragma unroll
    for (int k = 0; k < 6; ++k) {
      int p = (threadIdx.x >> 3) + 32 * k;       // 192 (nl,t) runs
      int nl = p / TT, t = p - nl * TT;
      ushort4 v = *(const ushort4*)&sT[p * STP + l8 * 4];
      size_t off = ((size_t)(n0 + nl) * BT + b * TT + t) * CC + l8 * 4;
      *(ushort4*)(H + off) = v;
    }
  }
}

// ---- edges[].y = dis[col]; pad edge list to multiple of 16 with {m, 0} dummies.
__global__ __launch_bounds__(192) void k_wt(uint2* __restrict__ edges,
                                            const int* __restrict__ deg,
                                            int* __restrict__ degp,
                                            const float* __restrict__ dis) {
  int m = blockIdx.x;
  int j = threadIdx.x;
  int d = deg[m];
  int dp = (d + 15) & ~15;
  if (j < d) {
    unsigned int* e = (unsigned int*)(edges + m * MAXD + j);
    e[1] = __float_as_uint(dis[e[0]]);
  } else if (j < dp) {
    edges[m * MAXD + j] = make_uint2((unsigned int)m, 0u);  // weight 0.0f
  }
  if (j == 0) degp[m] = dp;
}

// ---- pure gather (v3, proven 52 us): D[m,q] = dis[m]*sum_e dis[col]*S[col,q]
__global__ __launch_bounds__(1024) void k_gather(const unsigned short* __restrict__ S,
                                                 const uint2* __restrict__ edges,
                                                 const int* __restrict__ degp,
                                                 const float* __restrict__ dis,
                                                 unsigned short* __restrict__ D) {
  int tid = threadIdx.x;
  int wid = __builtin_amdgcn_readfirstlane(tid >> 6);
  int lane = tid & 63;
  int m = blockIdx.x * 16 + wid;
  int d = degp[m];                      // padded to x16
  float dm = dis[m];
  const uint2* ep = edges + (size_t)m * MAXD;      // wave-uniform stream
  const unsigned short* Sy = S + blockIdx.y * FW;  // uniform base
  int lo2 = lane * 8;                              // per-lane ushort offset (16B)
  float a0 = 0.f, a1 = 0.f, a2 = 0.f, a3 = 0.f;
  float a4 = 0.f, a5 = 0.f, a6 = 0.f, a7 = 0.f;
  for (int e = 0; e < d; e += 8) {
    uint4 hv[8];
    float w[8];
    #pragma unroll
    for (int k = 0; k < 8; ++k) {
      uint2 ew = ep[e + k];             // scalar (batched s_load)
      w[k] = __uint_as_float(ew.y);
      hv[k] = *(const uint4*)(Sy + (int)ew.x * NC + lo2);
    }
    #pragma unroll
    for (int k = 0; k < 8; ++k) {
      float wk = w[k];
      a0 = fmaf(wk, blo(hv[k].x), a0); a1 = fmaf(wk, bhi(hv[k].x), a1);
      a2 = fmaf(wk, blo(hv[k].y), a2); a3 = fmaf(wk, bhi(hv[k].y), a3);
      a4 = fmaf(wk, blo(hv[k].z), a4); a5 = fmaf(wk, bhi(hv[k].z), a5);
      a6 = fmaf(wk, blo(hv[k].w), a6); a7 = fmaf(wk, bhi(hv[k].w), a7);
    }
  }
  int fo = blockIdx.y * FW + lo2;
  ushort8 o;
  o[0] = f2bf(dm * a0); o[1] = f2bf(dm * a1);
  o[2] = f2bf(dm * a2); o[3] = f2bf(dm * a3);
  o[4] = f2bf(dm * a4); o[5] = f2bf(dm * a5);
  o[6] = f2bf(dm * a6); o[7] = f2bf(dm * a7);
  *(ushort8*)(D + (size_t)m * NC + fo) = o;
}

// ---- gather2 + mix, fused with k_mix's PROVEN coalesced store (r7 lesson:
// per-lane scattered float4 stores caused 10x write amplification, 240 MB).
// Block = 4 nodes x 12 waves (768 thr): wave (nl,y) gathers node n0+nl chunk y
// (identical v3 loop), stashes bf16 G2 tile in LDS (bit-identical to the old
// global G2); barrier; wave (nl, tI=y) runs the identical k_mix 6-MFMA chain
// (af2 from LDS); sOut bounce; barrier; verbatim k_mix coalesced store
// (2x768 iters). Kills the G2 round-trip + k_mix's 62 MB pass + 1 launch gap.
__global__ __launch_bounds__(768, 6) void k_gmix(
    const unsigned short* __restrict__ G1,
    const unsigned short* __restrict__ H,
    const uint2* __restrict__ edges,
    const int* __restrict__ degp,
    const float* __restrict__ dis,
    const float* __restrict__ W,
    const float* __restrict__ bias,
    float* __restrict__ out) {
  __shared__ __align__(16) unsigned short sG2[4][NC];   // 12 KB
  __shared__ __align__(16) float sOut[192 * SOP];       // 25.3 KB
  int tid = threadIdx.x;
  int wid = __builtin_amdgcn_readfirstlane(tid >> 6);   // 0..11
  int lane = tid & 63;
  int y = wid >> 2;                                     // chunk 0..2
  int nl = wid & 3;                                     // node-local 0..3
  int n0 = blockIdx.x * 4;
  int m = n0 + nl;
  int d = degp[m];
  float dm = dis[m];
  const uint2* ep = edges + (size_t)m * MAXD;
  const unsigned short* Sy = G1 + y * FW;
  int lo2 = lane * 8;
  float a0 = 0.f, a1 = 0.f, a2 = 0.f, a3 = 0.f;
  float a4 = 0.f, a5 = 0.f, a6 = 0.f, a7 = 0.f;
  for (int e = 0; e < d; e += 8) {
    uint4 hv[8];
    float w[8];
    #pragma unroll
    for (int k = 0; k < 8; ++k) {
      uint2 ew = ep[e + k];             // scalar (batched s_load)
      w[k] = __uint_as_float(ew.y);
      hv[k] = *(const uint4*)(Sy + (int)ew.x * NC + lo2);
    }
    #pragma unroll
    for (int k = 0; k < 8; ++k) {
      float wk = w[k];
      a0 = fmaf(wk, blo(hv[k].x), a0); a1 = fmaf(wk, bhi(hv[k].x), a1);
      a2 = fmaf(wk, blo(hv[k].y), a2); a3 = fmaf(wk, bhi(hv[k].y), a3);
      a4 = fmaf(wk, blo(hv[k].z), a4); a5 = fmaf(wk, bhi(hv[k].z), a5);
      a6 = fmaf(wk, blo(hv[k].w), a6); a7 = fmaf(wk, bhi(hv[k].w), a7);
    }
  }
  ushort8 go;
  go[0] = f2bf(dm * a0); go[1] = f2bf(dm * a1);
  go[2] = f2bf(dm * a2); go[3] = f2bf(dm * a3);
  go[4] = f2bf(dm * a4); go[5] = f2bf(dm * a5);
  go[6] = f2bf(dm * a6); go[7] = f2bf(dm * a7);
  *(ushort8*)&sG2[nl][y * FW + lo2] = go;      // [bt*CC+c] flat, same space
  __syncthreads();
  // ---- mix phase: wave (nl, tI=y), identical math/order to old k_mix
  int lm = lane & 15, quad = lane >> 4;
  size_t abase = ((size_t)m * BT + y * 16 + lm) * CC + quad * 8;
  short8 af0 = *(const short8*)(H + abase);
  short8 af1 = *(const short8*)(G1 + abase);
  short8 af2 = *(const short8*)&sG2[nl][(y * 16 + lm) * CC + quad * 8];
  int r0l = nl * BT + y * 16;
  #pragma unroll
  for (int h = 0; h < 2; ++h) {
    float bs = bias[h * 16 + lm];
    f32x4 acc = {bs, bs, bs, bs};
    #pragma unroll
    for (int g = 0; g < 3; ++g) {
      short8 vh, vl;
      #pragma unroll
      for (int j = 0; j < 8; ++j) {
        int r = quad * 8 + j, c = h * 16 + lm;
        float w0 = W[(0 * CC + r) * CC + c];
        float w1 = W[(1 * CC + r) * CC + c];
        float w2 = W[(2 * CC + r) * CC + c];
        float w = (g == 0) ? (w0 + w1 + w2)
                 : (g == 1) ? (-w1 - 4.f * w2)
                            : (2.f * w2);
        unsigned short hi = f2bf(w);
        vh[j] = (short)hi;
        vl[j] = (short)f2bf(w - bf2f(hi));
      }
      short8 af = (g == 0) ? af0 : (g == 1) ? af1 : af2;
      acc = __builtin_amdgcn_mfma_f32_16x16x32_bf16(af, vh, acc, 0, 0, 0);
      acc = __builtin_amdgcn_mfma_f32_16x16x32_bf16(af, vl, acc, 0, 0, 0);
    }
    int o = h * 16 + lm;
    #pragma unroll
    for (int reg = 0; reg < 4; ++reg)
      sOut[(r0l + quad * 4 + reg) * SOP + o] = acc[reg];
  }
  __syncthreads();
  // ---- verbatim k_mix coalesced store: 1536 float4 runs, 2 x 768 threads
  #pragma unroll
  for (int j = 0; j < 2; ++j) {
    int idx = j * 768 + tid;
    int bo = idx / 12;                  // b*32 + o
    int fq = idx - bo * 12;
    int p0 = fq * 4;                    // elem within the 48-long (b,o) run
    float v[4];
    #pragma unroll
    for (int k = 0; k < 4; ++k) {
      int p = p0 + k;
      int pn = p / TT, t = p - pn * TT;
      int b = bo >> 5, o = bo & 31;
      v[k] = sOut[(pn * BT + b * TT + t) * SOP + o];
    }
    size_t base = (((size_t)bo * NN) + n0) * TT + p0;
    *(float4*)(out + base) = make_float4(v[0], v[1], v[2], v[3]);
  }
}

extern "C" void kernel_launch(void* const* d_in, const int* in_sizes, int n_in,
                              void* d_out, int out_size, void* d_ws, size_t ws_size,
                              hipStream_t stream) {
  const float* x    = (const float*)d_in[0];
  const float* adj  = (const float*)d_in[1];
  const float* wgt  = (const float*)d_in[2];
  const float* bias = (const float*)d_in[3];
  char* ws = (char*)d_ws;
  float* dis  = (float*)ws;                                 // 16 KB
  int*   deg  = (int*)(ws + 16384);                         // 16 KB
  int*   degp = (int*)(ws + 32768);                         // 16 KB
  uint2* edges = (uint2*)(ws + 49152);                      // 6.29 MB
  char* p = ws + 49152 + (size_t)NN * MAXD * 8;
  unsigned short* H  = (unsigned short*)p;                  // 12.58 MB
  unsigned short* G1 = (unsigned short*)(p + (size_t)NN * NC * 2);

  k_build_trans<<<NN + 1024, 256, 0, stream>>>(adj, x, edges, deg, dis, H);
  k_wt<<<NN, 192, 0, stream>>>(edges, deg, degp, dis);
  k_gather<<<dim3(NN / 16, NCH), 1024, 0, stream>>>(H, edges, degp, dis, G1);
  k_gmix<<<NN / 4, 768, 0, stream>>>(G1, H, edges, degp, dis, wgt, bias,
                                     (float*)d_out);
}

// Round 9
// 251.345 us; speedup vs baseline: 1.2034x; 1.0130x over previous
//
#include <hip/hip_runtime.h>

#define NN 4096
#define CC 32
#define TT 12
#define BB 4
#define BT 48          // BB*TT
#define NC 1536        // BT*CC
#define MAXD 192       // mean degree ~82; P(deg>192) astronomically small
#define FW 512         // features per chunk (8/lane, 16B); chunk slice = 4096*1KB = 4MB
#define NCH 3          // NC / FW
#define STP 36         // k_trans LDS row stride (ushorts)
#define SOP 33         // sOut row stride (floats)

typedef float f32x4 __attribute__((ext_vector_type(4)));
typedef short short8 __attribute__((ext_vector_type(8)));
typedef unsigned short ushort8 __attribute__((ext_vector_type(8)));

__device__ __forceinline__ float bf2f(unsigned short h) {
  return __uint_as_float(((unsigned int)h) << 16);
}
__device__ __forceinline__ unsigned short f2bf(float f) {
  unsigned int u = __float_as_uint(f);
  return (unsigned short)((u + 0x7FFFu + ((u >> 16) & 1u)) >> 16);  // RNE
}
__device__ __forceinline__ float blo(unsigned int w) { return __uint_as_float(w << 16); }
__device__ __forceinline__ float bhi(unsigned int w) { return __uint_as_float(w & 0xFFFF0000u); }

// ---- fused: 4-wave ballot adjacency compaction (blocks [0,NN)) + x transpose
// (blocks [NN, NN+1024)). r8 subtraction showed atomic build ~50+ us (hidden
// under every top-5 cutoff). New build: wave w ballot-compacts quarter-row
// [w*1024,(w+1)*1024) in 16 UNROLLED iters into LDS (r6's failure was 1 wave
// x 64 serial iters + VGPR collapse), prefix over 4 counts, coalesced copy.
// Deterministic sorted edge order (r6 proved tolerance-safe).
__global__ __launch_bounds__(256) void k_build_trans(const float* __restrict__ adj,
                                                     const float* __restrict__ x,
                                                     uint2* __restrict__ edges,
                                                     int* __restrict__ deg,
                                                     float* __restrict__ dis,
                                                     unsigned short* __restrict__ H) {
  __shared__ unsigned short sT[192 * STP];
  __shared__ unsigned short lcol[4][1024];
  __shared__ int wcnt[4];
  if (blockIdx.x < NN) {
    int m = blockIdx.x;
    int w = threadIdx.x >> 6, lane = threadIdx.x & 63;
    const float* row = adj + (size_t)m * NN + w * 1024;
    unsigned long long ltmask = (1ull << lane) - 1ull;   // lane 63 -> 2^63-1, ok
    int cnt = 0;
    #pragma unroll
    for (int it = 0; it < 16; ++it) {
      float f = row[it * 64 + lane];
      unsigned long long ball = __ballot(f != 0.0f);
      if (f != 0.0f)
        lcol[w][cnt + __popcll(ball & ltmask)] = (unsigned short)(w * 1024 + it * 64 + lane);
      cnt += __popcll(ball);
    }
    if (lane == 0) wcnt[w] = cnt;
    __syncthreads();
    int c0 = wcnt[0], c1 = wcnt[1], c2 = wcnt[2], c3 = wcnt[3];
    int base = (w == 0) ? 0 : (w == 1) ? c0 : (w == 2) ? c0 + c1 : c0 + c1 + c2;
    int total = c0 + c1 + c2 + c3;
    unsigned int* ecol = (unsigned int*)(edges + m * MAXD);
    for (int i = lane; i < cnt; i += 64) {
      int p = base + i;
      if (p < MAXD) ecol[p * 2] = (unsigned int)lcol[w][i];
    }
    if (threadIdx.x == 0) {
      int d = total < MAXD ? total : MAXD;
      deg[m] = d;
      dis[m] = d > 0 ? (float)(1.0 / sqrt((double)d)) : 0.0f;
    }
  } else {
    int bx = blockIdx.x - NN;
    int b = bx >> 8;
    int n0 = (bx & 255) * 16;
    int c = threadIdx.x >> 3;        // 32 c-groups
    int l8 = threadIdx.x & 7;
    size_t base = ((size_t)(b * CC + c) * NN + n0) * TT;  // 192 contiguous floats
    #pragma unroll
    for (int it = 0; it < 6; ++it) {
      int j0 = it * 32 + l8 * 4;                 // j = nl*12 + t
      float4 f = *(const float4*)(x + base + j0);
      sT[(j0 + 0) * STP + c] = f2bf(f.x);
      sT[(j0 + 1) * STP + c] = f2bf(f.y);
      sT[(j0 + 2) * STP + c] = f2bf(f.z);
      sT[(j0 + 3) * STP + c] = f2bf(f.w);
    }
    __syncthreads();
    #pragma unroll
    for (int k = 0; k < 6; ++k) {
      int p = (threadIdx.x >> 3) + 32 * k;       // 192 (nl,t) runs
      int nl = p / TT, t = p - nl * TT;
      ushort4 v = *(const ushort4*)&sT[p * STP + l8 * 4];
      size_t off = ((size_t)(n0 + nl) * BT + b * TT + t) * CC + l8 * 4;
      *(ushort4*)(H + off) = v;
    }
  }
}

// ---- edges[].y = dis[col]; pad edge list to multiple of 16 with {m, 0} dummies.
__global__ __launch_bounds__(192) void k_wt(uint2* __restrict__ edges,
                                            const int* __restrict__ deg,
                                            int* __restrict__ degp,
                                            const float* __restrict__ dis) {
  int m = blockIdx.x;
  int j = threadIdx.x;
  int d = deg[m];
  int dp = (d + 15) & ~15;
  if (j < d) {
    unsigned int* e = (unsigned int*)(edges + m * MAXD + j);
    e[1] = __float_as_uint(dis[e[0]]);
  } else if (j < dp) {
    edges[m * MAXD + j] = make_uint2((unsigned int)m, 0u);  // weight 0.0f
  }
  if (j == 0) degp[m] = dp;
}

// ---- pure gather (v3, proven 52 us): D[m,q] = dis[m]*sum_e dis[col]*S[col,q]
__global__ __launch_bounds__(1024) void k_gather(const unsigned short* __restrict__ S,
                                                 const uint2* __restrict__ edges,
                                                 const int* __restrict__ degp,
                                                 const float* __restrict__ dis,
                                                 unsigned short* __restrict__ D) {
  int tid = threadIdx.x;
  int wid = __builtin_amdgcn_readfirstlane(tid >> 6);
  int lane = tid & 63;
  int m = blockIdx.x * 16 + wid;
  int d = degp[m];                      // padded to x16
  float dm = dis[m];
  const uint2* ep = edges + (size_t)m * MAXD;      // wave-uniform stream
  const unsigned short* Sy = S + blockIdx.y * FW;  // uniform base
  int lo2 = lane * 8;                              // per-lane ushort offset (16B)
  float a0 = 0.f, a1 = 0.f, a2 = 0.f, a3 = 0.f;
  float a4 = 0.f, a5 = 0.f, a6 = 0.f, a7 = 0.f;
  for (int e = 0; e < d; e += 8) {
    uint4 hv[8];
    float w[8];
    #pragma unroll
    for (int k = 0; k < 8; ++k) {
      uint2 ew = ep[e + k];             // scalar (batched s_load)
      w[k] = __uint_as_float(ew.y);
      hv[k] = *(const uint4*)(Sy + (int)ew.x * NC + lo2);
    }
    #pragma unroll
    for (int k = 0; k < 8; ++k) {
      float wk = w[k];
      a0 = fmaf(wk, blo(hv[k].x), a0); a1 = fmaf(wk, bhi(hv[k].x), a1);
      a2 = fmaf(wk, blo(hv[k].y), a2); a3 = fmaf(wk, bhi(hv[k].y), a3);
      a4 = fmaf(wk, blo(hv[k].z), a4); a5 = fmaf(wk, bhi(hv[k].z), a5);
      a6 = fmaf(wk, blo(hv[k].w), a6); a7 = fmaf(wk, bhi(hv[k].w), a7);
    }
  }
  int fo = blockIdx.y * FW + lo2;
  ushort8 o;
  o[0] = f2bf(dm * a0); o[1] = f2bf(dm * a1);
  o[2] = f2bf(dm * a2); o[3] = f2bf(dm * a3);
  o[4] = f2bf(dm * a4); o[5] = f2bf(dm * a5);
  o[6] = f2bf(dm * a6); o[7] = f2bf(dm * a7);
  *(ushort8*)(D + (size_t)m * NC + fo) = o;
}

// ---- gather2 + mix fused, CHUNK-LOCAL (r8 lesson: all-3-chunks-per-block
// blows the 4MB/XCD L2 -> FETCH 252MB). Grid (NN/16, NCH) like v3: one chunk
// slice hot per XCD. Wave (m,y)'s G2 accumulators = exactly one MFMA A-tile
// (16 bt x 32 c): lane-permute via 1KB wave-private LDS -> af2; af0/af1
// coalesced from H/G1 y-slice; identical k_mix MFMA chain; block-level sOut
// transpose over 16 nodes; per-segment coalesced stores (chunk y = two
// (b,t-run) segments, runs of 4/8/12 floats x 16 adjacent nodes; write amp
// 1.5x, not r7's 10x).
#define SEGST(bS, tS, lS, rr) {                                              \
    const int nq = (lS) / 4;                                                 \
    int o = (rr) / (16 * nq);                                                \
    int rem = (rr) - o * (16 * nq);                                          \
    int nl = rem / nq, q = rem - nl * nq;                                    \
    int rw = (bS) * 12 + (tS) + q * 4 - yy * 16;                             \
    float4 v = make_float4(sOut[nl][rw + 0][o], sOut[nl][rw + 1][o],         \
                           sOut[nl][rw + 2][o], sOut[nl][rw + 3][o]);        \
    size_t gb = (((size_t)((bS) * CC + o) * NN) + n0 + nl) * TT + (tS) + q * 4; \
    *(float4*)(out + gb) = v; }

__global__ __launch_bounds__(1024) void k_gmix(
    const unsigned short* __restrict__ G1,
    const unsigned short* __restrict__ H,
    const uint2* __restrict__ edges,
    const int* __restrict__ degp,
    const float* __restrict__ dis,
    const float* __restrict__ W,
    const float* __restrict__ bias,
    float* __restrict__ out) {
  __shared__ __align__(16) unsigned short sG2[16][16][CC];  // 16 KB, wave-private
  __shared__ __align__(16) float sOut[16][16][SOP];         // 33.8 KB
  int tid = threadIdx.x;
  int wid = __builtin_amdgcn_readfirstlane(tid >> 6);
  int lane = tid & 63;
  int n0 = blockIdx.x * 16;
  int m = n0 + wid;
  int yy = blockIdx.y;
  int d = degp[m];
  float dm = dis[m];
  const uint2* ep = edges + (size_t)m * MAXD;
  const unsigned short* Sy = G1 + yy * FW;
  int lo2 = lane * 8;
  float a0 = 0.f, a1 = 0.f, a2 = 0.f, a3 = 0.f;
  float a4 = 0.f, a5 = 0.f, a6 = 0.f, a7 = 0.f;
  for (int e = 0; e < d; e += 8) {
    uint4 hv[8];
    float w[8];
    #pragma unroll
    for (int k = 0; k < 8; ++k) {
      uint2 ew = ep[e + k];             // scalar (batched s_load)
      w[k] = __uint_as_float(ew.y);
      hv[k] = *(const uint4*)(Sy + (int)ew.x * NC + lo2);
    }
    #pragma unroll
    for (int k = 0; k < 8; ++k) {
      float wk = w[k];
      a0 = fmaf(wk, blo(hv[k].x), a0); a1 = fmaf(wk, bhi(hv[k].x), a1);
      a2 = fmaf(wk, blo(hv[k].y), a2); a3 = fmaf(wk, bhi(hv[k].y), a3);
      a4 = fmaf(wk, blo(hv[k].z), a4); a5 = fmaf(wk, bhi(hv[k].z), a5);
      a6 = fmaf(wk, blo(hv[k].w), a6); a7 = fmaf(wk, bhi(hv[k].w), a7);
    }
  }
  // G2 tile, bf16 -- bit-identical to the v3-stored G2 values
  ushort8 go;
  go[0] = f2bf(dm * a0); go[1] = f2bf(dm * a1);
  go[2] = f2bf(dm * a2); go[3] = f2bf(dm * a3);
  go[4] = f2bf(dm * a4); go[5] = f2bf(dm * a5);
  go[6] = f2bf(dm * a6); go[7] = f2bf(dm * a7);
  *(ushort8*)&sG2[wid][lane >> 2][(lane & 3) * 8] = go;   // wave-private permute
  // ---- mix (identical math/order to proven k_mix)
  int lm = lane & 15, quad = lane >> 4;
  size_t abase = ((size_t)m * BT + yy * 16 + lm) * CC + quad * 8;
  short8 af0 = *(const short8*)(H + abase);
  short8 af1 = *(const short8*)(G1 + abase);
  short8 af2 = *(const short8*)&sG2[wid][lm][quad * 8];
  #pragma unroll
  for (int h = 0; h < 2; ++h) {
    float bs = bias[h * 16 + lm];
    f32x4 acc = {bs, bs, bs, bs};
    #pragma unroll
    for (int g = 0; g < 3; ++g) {
      short8 vh, vl;
      #pragma unroll
      for (int j = 0; j < 8; ++j) {
        int r = quad * 8 + j, c = h * 16 + lm;
        float w0 = W[(0 * CC + r) * CC + c];
        float w1 = W[(1 * CC + r) * CC + c];
        float w2 = W[(2 * CC + r) * CC + c];
        float w = (g == 0) ? (w0 + w1 + w2)
                 : (g == 1) ? (-w1 - 4.f * w2)
                            : (2.f * w2);
        unsigned short hi = f2bf(w);
        vh[j] = (short)hi;
        vl[j] = (short)f2bf(w - bf2f(hi));
      }
      short8 af = (g == 0) ? af0 : (g == 1) ? af1 : af2;
      acc = __builtin_amdgcn_mfma_f32_16x16x32_bf16(af, vh, acc, 0, 0, 0);
      acc = __builtin_amdgcn_mfma_f32_16x16x32_bf16(af, vl, acc, 0, 0, 0);
    }
    int o = h * 16 + lm;
    #pragma unroll
    for (int reg = 0; reg < 4; ++reg)
      sOut[wid][quad * 4 + reg][o] = acc[reg];
  }
  __syncthreads();
  // ---- per-segment coalesced stores: 2048 float4s, 2 per thread.
  // y-slice bt rows [16y,16y+16) -> segments: y0:(b0,t0,12)+(b1,t0,4)
  //                                  y1:(b1,t4,8)+(b2,t0,8)  y2:(b2,t8,4)+(b3,t0,12)
  if (yy == 0) {
    #pragma unroll
    for (int j = 0; j < 2; ++j) {
      int idx = j * 1024 + tid;
      if (idx < 1536) SEGST(0, 0, 12, idx) else SEGST(1, 0, 4, idx - 1536)
    }
  } else if (yy == 1) {
    #pragma unroll
    for (int j = 0; j < 2; ++j) {
      int idx = j * 1024 + tid;
      if (idx < 1024) SEGST(1, 4, 8, idx) else SEGST(2, 0, 8, idx - 1024)
    }
  } else {
    #pragma unroll
    for (int j = 0; j < 2; ++j) {
      int idx = j * 1024 + tid;
      if (idx < 512) SEGST(2, 8, 4, idx) else SEGST(3, 0, 12, idx - 512)
    }
  }
}

extern "C" void kernel_launch(void* const* d_in, const int* in_sizes, int n_in,
                              void* d_out, int out_size, void* d_ws, size_t ws_size,
                              hipStream_t stream) {
  const float* x    = (const float*)d_in[0];
  const float* adj  = (const float*)d_in[1];
  const float* wgt  = (const float*)d_in[2];
  const float* bias = (const float*)d_in[3];
  char* ws = (char*)d_ws;
  float* dis  = (float*)ws;                                 // 16 KB
  int*   deg  = (int*)(ws + 16384);                         // 16 KB
  int*   degp = (int*)(ws + 32768);                         // 16 KB
  uint2* edges = (uint2*)(ws + 49152);                      // 6.29 MB
  char* p = ws + 49152 + (size_t)NN * MAXD * 8;
  unsigned short* H  = (unsigned short*)p;                  // 12.58 MB
  unsigned short* G1 = (unsigned short*)(p + (size_t)NN * NC * 2);

  k_build_trans<<<NN + 1024, 256, 0, stream>>>(adj, x, edges, deg, dis, H);
  k_wt<<<NN, 192, 0, stream>>>(edges, deg, degp, dis);
  k_gather<<<dim3(NN / 16, NCH), 1024, 0, stream>>>(H, edges, degp, dis, G1);
  k_gmix<<<dim3(NN / 16, NCH), 1024, 0, stream>>>(G1, H, edges, degp, dis,
                                                  wgt, bias, (float*)d_out);
}

// Round 10
// 238.218 us; speedup vs baseline: 1.2697x; 1.0551x over previous
//
#include <hip/hip_runtime.h>

#define NN 4096
#define CC 32
#define TT 12
#define BB 4
#define BT 48          // BB*TT
#define NC 1536        // BT*CC
#define MAXD 192       // mean degree ~82; P(deg>192) astronomically small
#define FW 512         // features per chunk (8/lane, 16B); chunk slice = 4096*1KB = 4MB
#define NCH 3          // NC / FW
#define STP 36         // k_trans LDS row stride (ushorts)
#define SOP 33         // sOut row stride (floats)

typedef float f32x4 __attribute__((ext_vector_type(4)));
typedef short short8 __attribute__((ext_vector_type(8)));
typedef unsigned short ushort8 __attribute__((ext_vector_type(8)));

__device__ __forceinline__ float bf2f(unsigned short h) {
  return __uint_as_float(((unsigned int)h) << 16);
}
__device__ __forceinline__ unsigned short f2bf(float f) {
  unsigned int u = __float_as_uint(f);
  return (unsigned short)((u + 0x7FFFu + ((u >> 16) & 1u)) >> 16);  // RNE
}
__device__ __forceinline__ float blo(unsigned int w) { return __uint_as_float(w << 16); }
__device__ __forceinline__ float bhi(unsigned int w) { return __uint_as_float(w & 0xFFFF0000u); }

// ---- adjacency (fp32) compaction into edges[].x + degree + d^-1/2
// (r3 version, verbatim. r7-r9 lesson: every fused/ballot variant of this
// front-end REGRESSED 2-3x by cross-round subtraction; separate atomic build
// + separate trans ~27 us combined.)
__global__ __launch_bounds__(256) void k_build(const float* __restrict__ adj,
                                               uint2* __restrict__ edges,
                                               int* __restrict__ deg, float* __restrict__ dis) {
  __shared__ int cnt;
  int m = blockIdx.x;
  if (threadIdx.x == 0) cnt = 0;
  __syncthreads();
  unsigned int* ecol = (unsigned int*)(edges + m * MAXD);
  const uint4* row = (const uint4*)(adj + (size_t)m * NN);
  for (int i = threadIdx.x; i < NN / 4; i += 256) {
    uint4 v = row[i];
    unsigned int ws[4] = {v.x, v.y, v.z, v.w};
    #pragma unroll
    for (int k = 0; k < 4; ++k) {
      if (ws[k] != 0) {
        int p = atomicAdd(&cnt, 1);
        if (p < MAXD) ecol[p * 2] = (unsigned int)(i * 4 + k);
      }
    }
  }
  __syncthreads();
  if (threadIdx.x == 0) {
    int d = cnt < MAXD ? cnt : MAXD;
    deg[m] = d;
    dis[m] = d > 0 ? (float)(1.0 / sqrt((double)d)) : 0.0f;
  }
}

// ---- edges[].y = dis[col]; pad edge list to multiple of 16 with {m, 0} dummies.
__global__ __launch_bounds__(192) void k_wt(uint2* __restrict__ edges,
                                            const int* __restrict__ deg,
                                            int* __restrict__ degp,
                                            const float* __restrict__ dis) {
  int m = blockIdx.x;
  int j = threadIdx.x;
  int d = deg[m];
  int dp = (d + 15) & ~15;
  if (j < d) {
    unsigned int* e = (unsigned int*)(edges + m * MAXD + j);
    e[1] = __float_as_uint(dis[e[0]]);
  } else if (j < dp) {
    edges[m * MAXD + j] = make_uint2((unsigned int)m, 0u);  // weight 0.0f
  }
  if (j == 0) degp[m] = dp;
}

// ---- x[b][c][n][t] (fp32) -> H[n][bt][c] (bf16) via LDS transpose (r3 verbatim).
__global__ __launch_bounds__(256) void k_trans(const float* __restrict__ x,
                                               unsigned short* __restrict__ H) {
  __shared__ unsigned short sT[192 * STP];
  int b = blockIdx.x >> 8;
  int n0 = (blockIdx.x & 255) * 16;
  int c = threadIdx.x >> 3;        // 32 c-groups
  int l8 = threadIdx.x & 7;
  size_t base = ((size_t)(b * CC + c) * NN + n0) * TT;  // 192 contiguous floats per (b,c)
  #pragma unroll
  for (int it = 0; it < 6; ++it) {
    int j0 = it * 32 + l8 * 4;                 // j = nl*12 + t
    float4 f = *(const float4*)(x + base + j0);
    sT[(j0 + 0) * STP + c] = f2bf(f.x);
    sT[(j0 + 1) * STP + c] = f2bf(f.y);
    sT[(j0 + 2) * STP + c] = f2bf(f.z);
    sT[(j0 + 3) * STP + c] = f2bf(f.w);
  }
  __syncthreads();
  #pragma unroll
  for (int k = 0; k < 6; ++k) {
    int p = (threadIdx.x >> 3) + 32 * k;       // 192 (nl,t) runs
    int nl = p / TT, t = p - nl * TT;
    ushort4 v = *(const ushort4*)&sT[p * STP + l8 * 4];
    size_t off = ((size_t)(n0 + nl) * BT + b * TT + t) * CC + l8 * 4;
    *(ushort4*)(H + off) = v;
  }
}

// ---- pure gather (v3, proven 52 us): D[m,q] = dis[m]*sum_e dis[col]*S[col,q]
__global__ __launch_bounds__(1024) void k_gather(const unsigned short* __restrict__ S,
                                                 const uint2* __restrict__ edges,
                                                 const int* __restrict__ degp,
                                                 const float* __restrict__ dis,
                                                 unsigned short* __restrict__ D) {
  int tid = threadIdx.x;
  int wid = __builtin_amdgcn_readfirstlane(tid >> 6);
  int lane = tid & 63;
  int m = blockIdx.x * 16 + wid;
  int d = degp[m];                      // padded to x16
  float dm = dis[m];
  const uint2* ep = edges + (size_t)m * MAXD;      // wave-uniform stream
  const unsigned short* Sy = S + blockIdx.y * FW;  // uniform base
  int lo2 = lane * 8;                              // per-lane ushort offset (16B)
  float a0 = 0.f, a1 = 0.f, a2 = 0.f, a3 = 0.f;
  float a4 = 0.f, a5 = 0.f, a6 = 0.f, a7 = 0.f;
  for (int e = 0; e < d; e += 8) {
    uint4 hv[8];
    float w[8];
    #pragma unroll
    for (int k = 0; k < 8; ++k) {
      uint2 ew = ep[e + k];             // scalar (batched s_load)
      w[k] = __uint_as_float(ew.y);
      hv[k] = *(const uint4*)(Sy + (int)ew.x * NC + lo2);
    }
    #pragma unroll
    for (int k = 0; k < 8; ++k) {
      float wk = w[k];
      a0 = fmaf(wk, blo(hv[k].x), a0); a1 = fmaf(wk, bhi(hv[k].x), a1);
      a2 = fmaf(wk, blo(hv[k].y), a2); a3 = fmaf(wk, bhi(hv[k].y), a3);
      a4 = fmaf(wk, blo(hv[k].z), a4); a5 = fmaf(wk, bhi(hv[k].z), a5);
      a6 = fmaf(wk, blo(hv[k].w), a6); a7 = fmaf(wk, bhi(hv[k].w), a7);
    }
  }
  int fo = blockIdx.y * FW + lo2;
  ushort8 o;
  o[0] = f2bf(dm * a0); o[1] = f2bf(dm * a1);
  o[2] = f2bf(dm * a2); o[3] = f2bf(dm * a3);
  o[4] = f2bf(dm * a4); o[5] = f2bf(dm * a5);
  o[6] = f2bf(dm * a6); o[7] = f2bf(dm * a7);
  *(ushort8*)(D + (size_t)m * NC + fo) = o;
}

// ---- gather2 + mix fused, chunk-local (r9, 72.5 us) + sOut node-dim pad:
// r9's 1.33M bank conflicts = SEGST reads, nl stride 16*33=528 = 16 (mod 32)
// -> 16 nodes alias 2 banks (8-way). Pad to [16][17][33]: nl stride 561 = 17
// (mod 32), odd -> 16 distinct banks. Values identical.
#define SEGST(bS, tS, lS, rr) {                                              \
    const int nq = (lS) / 4;                                                 \
    int o = (rr) / (16 * nq);                                                \
    int rem = (rr) - o * (16 * nq);                                          \
    int nl = rem / nq, q = rem - nl * nq;                                    \
    int rw = (bS) * 12 + (tS) + q * 4 - yy * 16;                             \
    float4 v = make_float4(sOut[nl][rw + 0][o], sOut[nl][rw + 1][o],         \
                           sOut[nl][rw + 2][o], sOut[nl][rw + 3][o]);        \
    size_t gb = (((size_t)((bS) * CC + o) * NN) + n0 + nl) * TT + (tS) + q * 4; \
    *(float4*)(out + gb) = v; }

__global__ __launch_bounds__(1024) void k_gmix(
    const unsigned short* __restrict__ G1,
    const unsigned short* __restrict__ H,
    const uint2* __restrict__ edges,
    const int* __restrict__ degp,
    const float* __restrict__ dis,
    const float* __restrict__ W,
    const float* __restrict__ bias,
    float* __restrict__ out) {
  __shared__ __align__(16) unsigned short sG2[16][16][CC];  // 16 KB, wave-private
  __shared__ __align__(16) float sOut[16][17][SOP];         // 35.9 KB (node-dim pad)
  int tid = threadIdx.x;
  int wid = __builtin_amdgcn_readfirstlane(tid >> 6);
  int lane = tid & 63;
  int n0 = blockIdx.x * 16;
  int m = n0 + wid;
  int yy = blockIdx.y;
  int d = degp[m];
  float dm = dis[m];
  const uint2* ep = edges + (size_t)m * MAXD;
  const unsigned short* Sy = G1 + yy * FW;
  int lo2 = lane * 8;
  float a0 = 0.f, a1 = 0.f, a2 = 0.f, a3 = 0.f;
  float a4 = 0.f, a5 = 0.f, a6 = 0.f, a7 = 0.f;
  for (int e = 0; e < d; e += 8) {
    uint4 hv[8];
    float w[8];
    #pragma unroll
    for (int k = 0; k < 8; ++k) {
      uint2 ew = ep[e + k];             // scalar (batched s_load)
      w[k] = __uint_as_float(ew.y);
      hv[k] = *(const uint4*)(Sy + (int)ew.x * NC + lo2);
    }
    #pragma unroll
    for (int k = 0; k < 8; ++k) {
      float wk = w[k];
      a0 = fmaf(wk, blo(hv[k].x), a0); a1 = fmaf(wk, bhi(hv[k].x), a1);
      a2 = fmaf(wk, blo(hv[k].y), a2); a3 = fmaf(wk, bhi(hv[k].y), a3);
      a4 = fmaf(wk, blo(hv[k].z), a4); a5 = fmaf(wk, bhi(hv[k].z), a5);
      a6 = fmaf(wk, blo(hv[k].w), a6); a7 = fmaf(wk, bhi(hv[k].w), a7);
    }
  }
  // G2 tile, bf16 -- bit-identical to the v3-stored G2 values
  ushort8 go;
  go[0] = f2bf(dm * a0); go[1] = f2bf(dm * a1);
  go[2] = f2bf(dm * a2); go[3] = f2bf(dm * a3);
  go[4] = f2bf(dm * a4); go[5] = f2bf(dm * a5);
  go[6] = f2bf(dm * a6); go[7] = f2bf(dm * a7);
  *(ushort8*)&sG2[wid][lane >> 2][(lane & 3) * 8] = go;   // wave-private permute
  // ---- mix (identical math/order to proven k_mix)
  int lm = lane & 15, quad = lane >> 4;
  size_t abase = ((size_t)m * BT + yy * 16 + lm) * CC + quad * 8;
  short8 af0 = *(const short8*)(H + abase);
  short8 af1 = *(const short8*)(G1 + abase);
  short8 af2 = *(const short8*)&sG2[wid][lm][quad * 8];
  #pragma unroll
  for (int h = 0; h < 2; ++h) {
    float bs = bias[h * 16 + lm];
    f32x4 acc = {bs, bs, bs, bs};
    #pragma unroll
    for (int g = 0; g < 3; ++g) {
      short8 vh, vl;
      #pragma unroll
      for (int j = 0; j < 8; ++j) {
        int r = quad * 8 + j, c = h * 16 + lm;
        float w0 = W[(0 * CC + r) * CC + c];
        float w1 = W[(1 * CC + r) * CC + c];
        float w2 = W[(2 * CC + r) * CC + c];
        float w = (g == 0) ? (w0 + w1 + w2)
                 : (g == 1) ? (-w1 - 4.f * w2)
                            : (2.f * w2);
        unsigned short hi = f2bf(w);
        vh[j] = (short)hi;
        vl[j] = (short)f2bf(w - bf2f(hi));
      }
      short8 af = (g == 0) ? af0 : (g == 1) ? af1 : af2;
      acc = __builtin_amdgcn_mfma_f32_16x16x32_bf16(af, vh, acc, 0, 0, 0);
      acc = __builtin_amdgcn_mfma_f32_16x16x32_bf16(af, vl, acc, 0, 0, 0);
    }
    int o = h * 16 + lm;
    #pragma unroll
    for (int reg = 0; reg < 4; ++reg)
      sOut[wid][quad * 4 + reg][o] = acc[reg];
  }
  __syncthreads();
  // ---- per-segment coalesced stores: 2048 float4s, 2 per thread.
  // y0:(b0,t0,12)+(b1,t0,4)  y1:(b1,t4,8)+(b2,t0,8)  y2:(b2,t8,4)+(b3,t0,12)
  if (yy == 0) {
    #pragma unroll
    for (int j = 0; j < 2; ++j) {
      int idx = j * 1024 + tid;
      if (idx < 1536) SEGST(0, 0, 12, idx) else SEGST(1, 0, 4, idx - 1536)
    }
  } else if (yy == 1) {
    #pragma unroll
    for (int j = 0; j < 2; ++j) {
      int idx = j * 1024 + tid;
      if (idx < 1024) SEGST(1, 4, 8, idx) else SEGST(2, 0, 8, idx - 1024)
    }
  } else {
    #pragma unroll
    for (int j = 0; j < 2; ++j) {
      int idx = j * 1024 + tid;
      if (idx < 512) SEGST(2, 8, 4, idx) else SEGST(3, 0, 12, idx - 512)
    }
  }
}

extern "C" void kernel_launch(void* const* d_in, const int* in_sizes, int n_in,
                              void* d_out, int out_size, void* d_ws, size_t ws_size,
                              hipStream_t stream) {
  const float* x    = (const float*)d_in[0];
  const float* adj  = (const float*)d_in[1];
  const float* wgt  = (const float*)d_in[2];
  const float* bias = (const float*)d_in[3];
  char* ws = (char*)d_ws;
  float* dis  = (float*)ws;                                 // 16 KB
  int*   deg  = (int*)(ws + 16384);                         // 16 KB
  int*   degp = (int*)(ws + 32768);                         // 16 KB
  uint2* edges = (uint2*)(ws + 49152);                      // 6.29 MB
  char* p = ws + 49152 + (size_t)NN * MAXD * 8;
  unsigned short* H  = (unsigned short*)p;                  // 12.58 MB
  unsigned short* G1 = (unsigned short*)(p + (size_t)NN * NC * 2);

  k_build<<<NN, 256, 0, stream>>>(adj, edges, deg, dis);
  k_wt<<<NN, 192, 0, stream>>>(edges, deg, degp, dis);
  k_trans<<<1024, 256, 0, stream>>>(x, H);
  k_gather<<<dim3(NN / 16, NCH), 1024, 0, stream>>>(H, edges, degp, dis, G1);
  k_gmix<<<dim3(NN / 16, NCH), 1024, 0, stream>>>(G1, H, edges, degp, dis,
                                                  wgt, bias, (float*)d_out);
}